// Round 11
// baseline (565.682 us; speedup 1.0000x reference)
//
#include <hip/hip_runtime.h>
#include <stdint.h>

#define NROWS   131072
#define DDIM    256
#define KDIM    768                   // 3 segments x 256
#define BM      256
#define BN      160
#define BK      64
#define NKT     (KDIM / BK)           // 12 K-tiles
#define NWG     4096                  // 512 row tiles x 8 col tiles
#define NELEM   ((size_t)NROWS * DDIM)

#define ABY     32768                 // A tile 256x64x2
#define BUFB    53248                 // + B tile 160x64x2 = 20480
#define WS_A_BYTES ((size_t)NROWS * KDIM * 2)          // 201,326,592
#define WS_B_OFF   WS_A_BYTES
#define WS_B_BYTES ((size_t)8 * BN * KDIM * 2)         // 1,966,080
#define WS_NEEDED  (WS_A_BYTES + WS_B_BYTES)

typedef __attribute__((ext_vector_type(8))) short  vbf16x8;
typedef __attribute__((ext_vector_type(4))) float  vf32x4;
typedef __attribute__((ext_vector_type(4))) unsigned int vu32x4;

__device__ __forceinline__ unsigned pk2(float hi, float lo) {
  return __builtin_amdgcn_perm(__float_as_uint(hi), __float_as_uint(lo), 0x07060302u);
}
__device__ __forceinline__ float sigm(float v)  { return 1.f / (1.f + __expf(-v)); }
__device__ __forceinline__ float tanh_(float v) { return 1.f - 2.f / (1.f + __expf(2.f * v)); }

__device__ __forceinline__ void gload16(const void* g, void* l) {
  __builtin_amdgcn_global_load_lds(
      (const __attribute__((address_space(1))) unsigned int*)g,
      (__attribute__((address_space(3))) unsigned int*)l, 16, 0, 0);
}

// ---- prepass A (R6-proven): x|lh|rh fp32 -> A_ws bf16 [131072][768], ----
// swizzle BAKED: within each 128B K-subtile, 16B-group p holds logical group p^(r&7)
__global__ __launch_bounds__(256) void prep_a(const float* __restrict__ x,
                                              const float* __restrict__ lh,
                                              const float* __restrict__ rh,
                                              unsigned short* __restrict__ A_ws)
{
  unsigned gid = blockIdx.x * 256u + threadIdx.x;   // < 131072*96
  unsigned r   = gid / 96u;
  unsigned gc  = gid - r * 96u;                     // logical 8-elem group 0..95
  const float* src = (gc < 32u) ? x : (gc < 64u ? lh : rh);
  const float4* s = (const float4*)(src + (size_t)r * 256u + (gc & 31u) * 8u);
  float4 a0 = s[0], a1 = s[1];
  unsigned p  = (gc & 7u) ^ (r & 7u);               // T2 swizzle baked into data
  unsigned st = gc >> 3;
  vu32x4 v = { pk2(a0.y, a0.x), pk2(a0.w, a0.z), pk2(a1.y, a1.x), pk2(a1.w, a1.z) };
  *(vu32x4*)(A_ws + (size_t)r * 768u + st * 64u + p * 8u) = v;
}

// ---- prepass B (R6-proven): weights -> B_ws bf16 [8 cb][160 n][768], baked swizzle ----
// row n: gate=(n mod 80)>>4, dloc=(n>=80)*16+(n&15), d=cb*32+dloc
struct BPrm { const float* w[15]; };                 // [seg 0..2][gate 0..4]
__global__ __launch_bounds__(256) void prep_b(BPrm q, unsigned short* __restrict__ B_ws)
{
  unsigned gid = blockIdx.x * 256u + threadIdx.x;   // < 8*160*96 = 122880
  unsigned cb  = gid / 15360u;
  unsigned rem = gid - cb * 15360u;
  unsigned n   = rem / 96u;
  unsigned gc  = rem - n * 96u;
  unsigned seg  = gc >> 5;
  unsigned gate = (n >= 80u ? n - 80u : n) >> 4;
  unsigned dloc = (n >= 80u ? 16u : 0u) + (n & 15u);
  const float4* s = (const float4*)(q.w[seg * 5 + gate] +
                     (size_t)(cb * 32u + dloc) * 256u + (gc & 31u) * 8u);
  float4 a0 = s[0], a1 = s[1];
  unsigned p = (gc & 7u) ^ (n & 7u);
  vu32x4 v = { pk2(a0.y, a0.x), pk2(a0.w, a0.z), pk2(a1.y, a1.x), pk2(a1.w, a1.z) };
  *(vu32x4*)(B_ws + (size_t)(cb * 160u + n) * 768u + (gc >> 3) * 64u + p * 8u) = v;
}

// ---------------- main GEMM + fused epilogue ----------------
struct GPrm {
  const unsigned short *A, *B;
  const float *lc, *rc, *bcx, *bix, *bfx, *box;
  float* out;
};

// 8-phase (T3+T4) port of the m201 template. 8 waves (4M x 2N), wave tile
// 64x80, acc[4][5]. BK=64, double-buffered 104KB LDS -> 1 block/CU (template's
// operating point). Per K-tile: 4 phases {ds_read subtile | stage slice ->
// raw barrier -> lgkmcnt(0) -> setprio+10 MFMA -> barrier}. stage(kt+1) fully
// issued in phases 0-1, so the single boundary vmcnt(0) finds loads that have
// flown >= 2 phases (~780 cyc). R6-proven baked swizzle, 0 conflicts.
__global__ __launch_bounds__(512, 2) void gemm_fused(GPrm p)
{
  const int t   = threadIdx.x;
  const int bid = blockIdx.x;
  // XCD A-affinity: j=XCD; 8 consecutive same-XCD blocks share one A panel.
  const int j   = bid & 7;
  const int g   = bid >> 3;
  const int cb  = g & 7;
  const int rowBase = ((g >> 3) * 8 + j) * BM;

  __shared__ char Lds[2 * BUFB];       // 2 x (A 32KB | B 20KB)

  const int l  = t & 63;
  const int w  = t >> 6;               // 0..7
  const int lm = l & 15;
  const int lk = l >> 4;
  const int wr = w >> 1;               // 0..3: 64 rows each
  const int wc = w & 1;                // 0..1: 80 cols each

  // staging lanes: 1KB/call = 8 rows x 8 x 16B; source swizzle baked in data
  const int lr8 = l >> 3;              // 0..7 row within call
  const int lg8 = l & 7;               // 0..7 16B group within 128B row

  // per-lane global source bases
  const unsigned short* aSrc = p.A + (size_t)(rowBase + w * 32 + lr8) * 768 + lg8 * 8;
  const unsigned short* bSrc = p.B + (size_t)(cb * 160 + lr8) * 768 + lg8 * 8;

  // ds_read bases; XOR swizzle depends only on lm&7 (row = mult-of-16 + lm)
  const int x0 = (lk * 16) ^ ((lm & 7) << 4);        // ks=0
  const int x1 = (64 + lk * 16) ^ ((lm & 7) << 4);   // ks=1
  int aRow[4], bRow[5];
#pragma unroll
  for (int m = 0; m < 4; ++m) aRow[m] = (wr * 64 + m * 16 + lm) * 128;
#pragma unroll
  for (int n = 0; n < 5; ++n) bRow[n] = ABY + (wc * 80 + n * 16 + lm) * 128;

  vf32x4 acc[4][5];
#pragma unroll
  for (int m = 0; m < 4; ++m)
#pragma unroll
    for (int n = 0; n < 5; ++n) acc[m][n] = (vf32x4)(0.f);

  // stage slices: A = 32 calls (4/wave), B = 20 calls (wave w: w, w+8, +16 if w<4)
  auto stageA = [&](int kt, int buf) {
    const unsigned short* s = aSrc + kt * 64;
    char* dst = &Lds[buf * BUFB] + (w * 32) * 128;
#pragma unroll
    for (int c = 0; c < 4; ++c)
      gload16(s + (size_t)c * 8 * 768, dst + c * 1024);
  };
  auto stageB = [&](int kt, int buf) {
    const unsigned short* s = bSrc + kt * 64;
    char* dst = &Lds[buf * BUFB] + ABY;
    gload16(s + (size_t)w * 8 * 768,        dst + w * 1024);
    gload16(s + (size_t)(w + 8) * 8 * 768,  dst + (w + 8) * 1024);
    if (w < 4)
      gload16(s + (size_t)(w + 16) * 8 * 768, dst + (w + 16) * 1024);
  };

  // prologue: stage K-tile 0 into buf 0
  stageA(0, 0);
  stageB(0, 0);

  vbf16x8 bf[5], af0, af1;
  for (int kt = 0; kt < NKT; ++kt) {
    const int cur = kt & 1;
    const char* L = &Lds[cur * BUFB];
    // K-tile boundary: only tile-kt loads outstanding -> this wait is counted
    asm volatile("s_waitcnt vmcnt(0)" ::: "memory");
    __builtin_amdgcn_s_barrier();      // all waves' DMA for kt landed

    // ---- P0: af(m0,m1) + bf, ks=0 ; stage A(kt+1) ----
    af0 = *(const vbf16x8*)(L + aRow[0] + x0);
    af1 = *(const vbf16x8*)(L + aRow[1] + x0);
#pragma unroll
    for (int n = 0; n < 5; ++n) bf[n] = *(const vbf16x8*)(L + bRow[n] + x0);
    if (kt < NKT - 1) stageA(kt + 1, cur ^ 1);
    asm volatile("" ::: "memory");
    __builtin_amdgcn_s_barrier();
    asm volatile("s_waitcnt lgkmcnt(0)" ::: "memory");
    __builtin_amdgcn_sched_barrier(0);
    __builtin_amdgcn_s_setprio(1);
#pragma unroll
    for (int n = 0; n < 5; ++n) {
      acc[0][n] = __builtin_amdgcn_mfma_f32_16x16x32_bf16(af0, bf[n], acc[0][n], 0, 0, 0);
      acc[1][n] = __builtin_amdgcn_mfma_f32_16x16x32_bf16(af1, bf[n], acc[1][n], 0, 0, 0);
    }
    __builtin_amdgcn_s_setprio(0);
    __builtin_amdgcn_s_barrier();

    // ---- P1: af(m2,m3) ks=0 (bf reused) ; stage B(kt+1) ----
    af0 = *(const vbf16x8*)(L + aRow[2] + x0);
    af1 = *(const vbf16x8*)(L + aRow[3] + x0);
    if (kt < NKT - 1) stageB(kt + 1, cur ^ 1);
    asm volatile("" ::: "memory");
    __builtin_amdgcn_s_barrier();
    asm volatile("s_waitcnt lgkmcnt(0)" ::: "memory");
    __builtin_amdgcn_sched_barrier(0);
    __builtin_amdgcn_s_setprio(1);
#pragma unroll
    for (int n = 0; n < 5; ++n) {
      acc[2][n] = __builtin_amdgcn_mfma_f32_16x16x32_bf16(af0, bf[n], acc[2][n], 0, 0, 0);
      acc[3][n] = __builtin_amdgcn_mfma_f32_16x16x32_bf16(af1, bf[n], acc[3][n], 0, 0, 0);
    }
    __builtin_amdgcn_s_setprio(0);
    __builtin_amdgcn_s_barrier();

    // ---- P2: af(m0,m1) + bf, ks=1 ----
    af0 = *(const vbf16x8*)(L + aRow[0] + x1);
    af1 = *(const vbf16x8*)(L + aRow[1] + x1);
#pragma unroll
    for (int n = 0; n < 5; ++n) bf[n] = *(const vbf16x8*)(L + bRow[n] + x1);
    asm volatile("" ::: "memory");
    __builtin_amdgcn_s_barrier();
    asm volatile("s_waitcnt lgkmcnt(0)" ::: "memory");
    __builtin_amdgcn_sched_barrier(0);
    __builtin_amdgcn_s_setprio(1);
#pragma unroll
    for (int n = 0; n < 5; ++n) {
      acc[0][n] = __builtin_amdgcn_mfma_f32_16x16x32_bf16(af0, bf[n], acc[0][n], 0, 0, 0);
      acc[1][n] = __builtin_amdgcn_mfma_f32_16x16x32_bf16(af1, bf[n], acc[1][n], 0, 0, 0);
    }
    __builtin_amdgcn_s_setprio(0);
    __builtin_amdgcn_s_barrier();

    // ---- P3: af(m2,m3) ks=1 ----
    af0 = *(const vbf16x8*)(L + aRow[2] + x1);
    af1 = *(const vbf16x8*)(L + aRow[3] + x1);
    asm volatile("" ::: "memory");
    __builtin_amdgcn_s_barrier();
    asm volatile("s_waitcnt lgkmcnt(0)" ::: "memory");
    __builtin_amdgcn_sched_barrier(0);
    __builtin_amdgcn_s_setprio(1);
#pragma unroll
    for (int n = 0; n < 5; ++n) {
      acc[2][n] = __builtin_amdgcn_mfma_f32_16x16x32_bf16(af0, bf[n], acc[2][n], 0, 0, 0);
      acc[3][n] = __builtin_amdgcn_mfma_f32_16x16x32_bf16(af1, bf[n], acc[3][n], 0, 0, 0);
    }
    __builtin_amdgcn_s_setprio(0);
    __builtin_amdgcn_s_barrier();
  }

  // ---- fused epilogue: 5 gates for (row, d) live in acc[m][0..4] ----
  const int dcol = cb * 32 + wc * 16 + lm;
  const float bu  = p.bcx[dcol];
  const float bi  = p.bix[dcol];
  const float bff = p.bfx[dcol];
  const float bo_ = p.box[dcol];
#pragma unroll
  for (int m = 0; m < 4; ++m) {
    const int r0 = rowBase + wr * 64 + m * 16 + lk * 4;
#pragma unroll
    for (int jj = 0; jj < 4; ++jj) {
      const size_t off = (size_t)(r0 + jj) * DDIM + dcol;
      const float pu  = acc[m][0][jj] + bu;
      const float pi  = acc[m][1][jj] + bi;
      const float plf = acc[m][2][jj] + bff;
      const float prf = acc[m][3][jj] + bff;
      const float po  = acc[m][4][jj] + bo_;
      const float u  = tanh_(pu);
      const float ig = sigm(pi);
      const float lf = sigm(plf);
      const float rf = sigm(prf);
      const float og = sigm(po);
      const float c  = ig * u + lf * p.lc[off] + rf * p.rc[off];
      const float hh = og * tanh_(c);
      p.out[off]         = c;
      p.out[NELEM + off] = hh;
    }
  }
}

// ---------------- fallback (R3 kernel, used only if ws too small) ----------------
struct Params {
  const float *x, *lh, *rh, *lc, *rc;
  const float *s0g0, *s0g1, *s0g2, *s0g3, *s0g4;
  const float *s1g0, *s1g1, *s1g2, *s1g3, *s1g4;
  const float *s2g0, *s2g1, *s2g2, *s2g3, *s2g4;
  const float *bcx, *bix, *bfx, *box;
  float *out;
};
__global__ __launch_bounds__(256, 2) void fused_tree_cell_fb(Params p)
{
  const int t   = threadIdx.x;
  const int bid = blockIdx.x;
  const int nbid    = (bid & 7) * 1024 + (bid >> 3);
  const int tileRow = nbid >> 3;
  const int cb      = nbid & 7;
  const int rowBase = tileRow * 128;
  __shared__ short Ash[128 * 64];
  __shared__ short Bsh[160 * 64];
  const int l  = t & 63;
  const int lm = l & 15;
  const int lk = l >> 4;
  const int w  = t >> 6;
  const int wr = w >> 1;
  const int wc = w & 1;
  vf32x4 acc[4][5];
#pragma unroll
  for (int m = 0; m < 4; ++m)
#pragma unroll
    for (int n = 0; n < 5; ++n) acc[m][n] = (vf32x4)(0.f);
  float4 aR[4][2];
  float4 bR[5][2];
  const int tg  = t >> 3;
  const int kc  = (t & 7) * 8;
  const int kcB = kc * 2;
  auto stage_load = [&](int kt) {
    const int seg  = kt >> 2;
    const int ksub = (kt & 3) * 64;
    const float *ap, *g0, *g1, *g2, *g3, *g4;
    if (seg == 0)      { ap = p.x;  g0 = p.s0g0; g1 = p.s0g1; g2 = p.s0g2; g3 = p.s0g3; g4 = p.s0g4; }
    else if (seg == 1) { ap = p.lh; g0 = p.s1g0; g1 = p.s1g1; g2 = p.s1g2; g3 = p.s1g3; g4 = p.s1g4; }
    else               { ap = p.rh; g0 = p.s2g0; g1 = p.s2g1; g2 = p.s2g2; g3 = p.s2g3; g4 = p.s2g4; }
#pragma unroll
    for (int ps = 0; ps < 4; ++ps) {
      const float* s = ap + (size_t)(rowBase + ps * 32 + tg) * DDIM + ksub + kc;
      aR[ps][0] = *(const float4*)s;
      aR[ps][1] = *(const float4*)(s + 4);
    }
#define BLOAD(ps, GA, GB) { \
    const float* bp = (t & 128) ? (GB) : (GA); \
    const int dloc = ((((ps) * 32) + tg) >= 80 ? 16 : 0) + (tg & 15); \
    const float* s = bp + (size_t)(cb * 32 + dloc) * DDIM + ksub + kc; \
    bR[ps][0] = *(const float4*)s; \
    bR[ps][1] = *(const float4*)(s + 4); }
    BLOAD(0, g0, g1) BLOAD(1, g2, g3) BLOAD(2, g4, g0) BLOAD(3, g1, g2) BLOAD(4, g3, g4)
#undef BLOAD
  };
  auto stage_write = [&]() {
    char* Ab = (char*)&Ash[0];
#pragma unroll
    for (int ps = 0; ps < 4; ++ps) {
      const int row  = ps * 32 + tg;
      const int byte = (row * 128 + kcB) ^ ((row & 7) << 4);
      vu32x4 v = { pk2(aR[ps][0].y, aR[ps][0].x), pk2(aR[ps][0].w, aR[ps][0].z),
                   pk2(aR[ps][1].y, aR[ps][1].x), pk2(aR[ps][1].w, aR[ps][1].z) };
      *(vu32x4*)(Ab + byte) = v;
    }
    char* Bb = (char*)&Bsh[0];
#pragma unroll
    for (int ps = 0; ps < 5; ++ps) {
      const int row  = ps * 32 + tg;
      const int byte = (row * 128 + kcB) ^ ((row & 7) << 4);
      vu32x4 v = { pk2(bR[ps][0].y, bR[ps][0].x), pk2(bR[ps][0].w, bR[ps][0].z),
                   pk2(bR[ps][1].y, bR[ps][1].x), pk2(bR[ps][1].w, bR[ps][1].z) };
      *(vu32x4*)(Bb + byte) = v;
    }
  };
  auto compute = [&]() {
    const char* Ab = (const char*)&Ash[0];
    const char* Bb = (const char*)&Bsh[0];
#pragma unroll
    for (int ks = 0; ks < 2; ++ks) {
      vbf16x8 af[4], bf[5];
#pragma unroll
      for (int m = 0; m < 4; ++m) {
        const int row  = wr * 64 + m * 16 + lm;
        const int byte = (row * 128 + ks * 64 + lk * 16) ^ ((row & 7) << 4);
        af[m] = *(const vbf16x8*)(Ab + byte);
      }
#pragma unroll
      for (int n = 0; n < 5; ++n) {
        const int row  = wc * 80 + n * 16 + lm;
        const int byte = (row * 128 + ks * 64 + lk * 16) ^ ((row & 7) << 4);
        bf[n] = *(const vbf16x8*)(Bb + byte);
      }
#pragma unroll
      for (int m = 0; m < 4; ++m)
#pragma unroll
        for (int n = 0; n < 5; ++n)
          acc[m][n] = __builtin_amdgcn_mfma_f32_16x16x32_bf16(af[m], bf[n], acc[m][n], 0, 0, 0);
    }
  };
  stage_load(0);
  stage_write();
  __syncthreads();
  for (int kt = 0; kt < 12; ++kt) {
    if (kt < 11) stage_load(kt + 1);
    compute();
    if (kt < 11) {
      __builtin_amdgcn_sched_barrier(0);
      __builtin_amdgcn_s_barrier();
      stage_write();
      __syncthreads();
    }
  }
  const int dcol = cb * 32 + wc * 16 + lm;
  const float bu  = p.bcx[dcol];
  const float bi  = p.bix[dcol];
  const float bff = p.bfx[dcol];
  const float bo  = p.box[dcol];
#pragma unroll
  for (int m = 0; m < 4; ++m) {
    const int r0 = rowBase + wr * 64 + m * 16 + lk * 4;
#pragma unroll
    for (int jj = 0; jj < 4; ++jj) {
      const size_t off = (size_t)(r0 + jj) * DDIM + dcol;
      const float pu  = acc[m][0][jj] + bu;
      const float pi  = acc[m][1][jj] + bi;
      const float plf = acc[m][2][jj] + bff;
      const float prf = acc[m][3][jj] + bff;
      const float po  = acc[m][4][jj] + bo;
      const float u  = tanh_(pu);
      const float ig = sigm(pi);
      const float lf = sigm(plf);
      const float rf = sigm(prf);
      const float og = sigm(po);
      const float c  = ig * u + lf * p.lc[off] + rf * p.rc[off];
      const float hh = og * tanh_(c);
      p.out[off]         = c;
      p.out[NELEM + off] = hh;
    }
  }
}

extern "C" void kernel_launch(void* const* d_in, const int* in_sizes, int n_in,
                              void* d_out, int out_size, void* d_ws, size_t ws_size,
                              hipStream_t stream)
{
  const float* x  = (const float*)d_in[0];
  const float* lc = (const float*)d_in[1];
  const float* lh = (const float*)d_in[2];
  const float* rc = (const float*)d_in[3];
  const float* rh = (const float*)d_in[4];
  const float* W_cx = (const float*)d_in[5];
  const float* b_cx = (const float*)d_in[6];
  const float* W_ox = (const float*)d_in[7];
  const float* b_ox = (const float*)d_in[8];
  const float* W_fx = (const float*)d_in[9];
  const float* b_fx = (const float*)d_in[10];
  const float* W_ix = (const float*)d_in[11];
  const float* b_ix = (const float*)d_in[12];
  const float* U_ilh  = (const float*)d_in[13];
  const float* U_irh  = (const float*)d_in[14];
  const float* U_lflh = (const float*)d_in[15];
  const float* U_lfrh = (const float*)d_in[16];
  const float* U_rflh = (const float*)d_in[17];
  const float* U_rfrh = (const float*)d_in[18];
  const float* U_ulh  = (const float*)d_in[19];
  const float* U_urh  = (const float*)d_in[20];
  const float* U_olh  = (const float*)d_in[21];
  const float* U_orh  = (const float*)d_in[22];

  if (ws_size >= WS_NEEDED && d_ws != nullptr) {
    unsigned short* A_ws = (unsigned short*)d_ws;
    unsigned short* B_ws = (unsigned short*)((char*)d_ws + WS_B_OFF);
    hipLaunchKernelGGL(prep_a, dim3(NROWS * 96 / 256), dim3(256), 0, stream, x, lh, rh, A_ws);
    BPrm q;
    q.w[0] = W_cx;  q.w[1] = W_ix;  q.w[2] = W_fx;   q.w[3] = W_fx;   q.w[4] = W_ox;
    q.w[5] = U_ulh; q.w[6] = U_ilh; q.w[7] = U_lflh; q.w[8] = U_rflh; q.w[9] = U_olh;
    q.w[10] = U_urh; q.w[11] = U_irh; q.w[12] = U_lfrh; q.w[13] = U_rfrh; q.w[14] = U_orh;
    hipLaunchKernelGGL(prep_b, dim3(8 * 160 * 96 / 256), dim3(256), 0, stream, q, B_ws);
    GPrm g;
    g.A = A_ws; g.B = B_ws; g.lc = lc; g.rc = rc;
    g.bcx = b_cx; g.bix = b_ix; g.bfx = b_fx; g.box = b_ox;
    g.out = (float*)d_out;
    hipLaunchKernelGGL(gemm_fused, dim3(NWG), dim3(512), 0, stream, g);
  } else {
    Params p;
    p.x = x; p.lc = lc; p.lh = lh; p.rc = rc; p.rh = rh;
    p.s0g0 = W_cx;  p.s0g1 = W_ix;  p.s0g2 = W_fx;   p.s0g3 = W_fx;   p.s0g4 = W_ox;
    p.s1g0 = U_ulh; p.s1g1 = U_ilh; p.s1g2 = U_lflh; p.s1g3 = U_rflh; p.s1g4 = U_olh;
    p.s2g0 = U_urh; p.s2g1 = U_irh; p.s2g2 = U_lfrh; p.s2g3 = U_rfrh; p.s2g4 = U_orh;
    p.bcx = b_cx; p.bix = b_ix; p.bfx = b_fx; p.box = b_ox;
    p.out = (float*)d_out;
    hipLaunchKernelGGL(fused_tree_cell_fb, dim3(8192), dim3(256), 0, stream, p);
  }
}

// Round 12
// 514.395 us; speedup vs baseline: 1.0997x; 1.0997x over previous
//
#include <hip/hip_runtime.h>
#include <stdint.h>

#define NROWS   131072
#define DDIM    256
#define KDIM    768                   // 3 segments x 256
#define BM      128
#define BN      160
#define BK      32
#define NKT     (KDIM / BK)           // 24 K-tiles
#define NWG     8192                  // 1024 row tiles x 8 col tiles
#define NELEM   ((size_t)NROWS * DDIM)

#define ABYTES  8192                  // A tile 128x32x2
#define BUFB    18432                 // + B tile 160x32x2 = 10240
#define WS_A_BYTES ((size_t)NROWS * KDIM * 2)          // 201,326,592
#define WS_B_OFF   WS_A_BYTES
#define WS_B_BYTES ((size_t)8 * BN * KDIM * 2)         // 1,966,080
#define WS_NEEDED  (WS_A_BYTES + WS_B_BYTES)

#define NB_B    480                   // prep blocks doing B (122880/256)
#define NB_A    49152                 // prep blocks doing A (131072*96/256)

typedef __attribute__((ext_vector_type(8))) short  vbf16x8;
typedef __attribute__((ext_vector_type(4))) float  vf32x4;
typedef __attribute__((ext_vector_type(4))) unsigned int vu32x4;

__device__ __forceinline__ unsigned pk2(float hi, float lo) {
  return __builtin_amdgcn_perm(__float_as_uint(hi), __float_as_uint(lo), 0x07060302u);
}
__device__ __forceinline__ float sigm(float v)  { return 1.f / (1.f + __expf(-v)); }
__device__ __forceinline__ float tanh_(float v) { return 1.f - 2.f / (1.f + __expf(2.f * v)); }

__device__ __forceinline__ void gload16(const void* g, void* l) {
  __builtin_amdgcn_global_load_lds(
      (const __attribute__((address_space(1))) unsigned int*)g,
      (__attribute__((address_space(3))) unsigned int*)l, 16, 0, 0);
}

// ---- merged prepass: one dispatch. Blocks [0,NB_B): B; [NB_B,+NB_A): A ----
// A: x|lh|rh fp32 -> A_ws bf16 [131072][768] row-major.
// B: weights -> B_ws bf16 [8 cb][160 n][768]; row n: gate=(n%80)>>4,
//    dloc=(n>=80)*16+(n&15), d=cb*32+dloc.
struct PPrm {
  const float* w[15];                  // [seg 0..2][gate 0..4]
  const float *x, *lh, *rh;
  unsigned short *A_ws, *B_ws;
};
__global__ __launch_bounds__(256) void prep_ab(PPrm q)
{
  const unsigned bid = blockIdx.x;
  if (bid < NB_B) {
    unsigned gid = bid * 256u + threadIdx.x;        // < 8*160*96
    unsigned cb  = gid / 15360u;
    unsigned rem = gid - cb * 15360u;
    unsigned n   = rem / 96u;
    unsigned gc  = rem - n * 96u;
    unsigned seg  = gc >> 5;
    unsigned gate = (n >= 80u ? n - 80u : n) >> 4;
    unsigned dloc = (n >= 80u ? 16u : 0u) + (n & 15u);
    const float4* s = (const float4*)(q.w[seg * 5 + gate] +
                       (size_t)(cb * 32u + dloc) * 256u + (gc & 31u) * 8u);
    float4 a0 = s[0], a1 = s[1];
    vu32x4 v = { pk2(a0.y, a0.x), pk2(a0.w, a0.z), pk2(a1.y, a1.x), pk2(a1.w, a1.z) };
    *(vu32x4*)(q.B_ws + (size_t)(cb * 160u + n) * 768u + gc * 8u) = v;
  } else {
    unsigned gid = (bid - NB_B) * 256u + threadIdx.x;   // < 131072*96
    unsigned r   = gid / 96u;
    unsigned gc  = gid - r * 96u;                   // 8-elem group 0..95
    const float* src = (gc < 32u) ? q.x : (gc < 64u ? q.lh : q.rh);
    const float4* s = (const float4*)(src + (size_t)r * 256u + (gc & 31u) * 8u);
    float4 a0 = s[0], a1 = s[1];
    vu32x4 v = { pk2(a0.y, a0.x), pk2(a0.w, a0.z), pk2(a1.y, a1.x), pk2(a1.w, a1.z) };
    *(vu32x4*)(q.A_ws + (size_t)r * 768u + gc * 8u) = v;
  }
}

// ---------------- main GEMM + fused epilogue ----------------
struct GPrm {
  const unsigned short *A, *B;
  const float *lc, *rc, *bcx, *bix, *bfx, *box;
  float* out;
};

// R10 structure (best measured: 428 us GEMM), polished:
// - K-loop FULLY unrolled; per-call src pointers precomputed once; per-step
//   global offsets are immediates (kt*64 <= 1472 B, fits 13-bit signed),
//   LDS dests compile-time -> removes ~35 VALU/SALU per K-step per wave.
// - acc[4][5], BK=32, 2x18KB LDS, 0-conflict baked swizzle, XCD A-affinity,
//   launch_bounds(256,3) -> ~3.6 blocks/CU measured.
__global__ __launch_bounds__(256, 3) void gemm_fused(GPrm p)
{
  const int t   = threadIdx.x;
  const int bid = blockIdx.x;
  const int j   = bid & 7;             // XCD
  const int g   = bid >> 3;
  const int cb  = g & 7;
  const int rowBase = ((g >> 3) * 8 + j) * BM;

  __shared__ char Lds[2 * BUFB];       // 2 x (A 8KB | B 10KB)

  const int l  = t & 63;
  const int w  = t >> 6;               // 0..3
  const int lm = l & 15;
  const int lk = l >> 4;
  const int wr = w >> 1;               // 0..1: 64 rows each
  const int wc = w & 1;                // 0..1: 80 cols each

  // staging lanes: 1KB/wave-call = 16 rows x 4 x 16B
  const int lr = l >> 2;               // 0..15 row within call
  const int lg = l & 3;                // 0..3  16B group
  const int sw = (lr >> 1) & 3;        // source-side XOR (0-conflict)

  // per-call global source base pointers (computed ONCE)
  const unsigned short* srcP[5];
  char* dstP[5];
  int ncall;
  if (w < 2) {
    ncall = 4;
    const unsigned short* a0 = p.A + (size_t)(rowBase + w * 64 + lr) * 768 + (lg ^ sw) * 8;
#pragma unroll
    for (int c = 0; c < 4; ++c) {
      srcP[c] = a0 + (size_t)c * 16 * 768;
      dstP[c] = &Lds[0] + w * 4096 + c * 1024;
    }
    srcP[4] = a0; dstP[4] = dstP[0];
  } else {
    ncall = 5;
    const unsigned short* b0 = p.B + (size_t)(cb * 160 + (w - 2) * 80 + lr) * 768 + (lg ^ sw) * 8;
#pragma unroll
    for (int c = 0; c < 5; ++c) {
      srcP[c] = b0 + (size_t)c * 16 * 768;
      dstP[c] = &Lds[0] + ABYTES + (w - 2) * 5120 + c * 1024;
    }
  }

  // ds_read per-lane base offsets; same XOR on read side (0 conflicts)
  const int xr  = (lk ^ ((lm >> 1) & 3)) << 4;
  const int aRd = (wr * 64 + lm) * 64 + xr;             // + m*1024
  const int bRd = ABYTES + (wc * 80 + lm) * 64 + xr;    // + n*1024

  vf32x4 acc[4][5];
#pragma unroll
  for (int m = 0; m < 4; ++m)
#pragma unroll
    for (int n = 0; n < 5; ++n) acc[m][n] = (vf32x4)(0.f);

  auto issue = [&](int kt) {            // kt compile-time under full unroll
    const int boff = (kt & 1) * BUFB;
    if (w < 2) {
#pragma unroll
      for (int c = 0; c < 4; ++c)
        gload16(srcP[c] + kt * 32, dstP[c] + boff);
    } else {
#pragma unroll
      for (int c = 0; c < 5; ++c)
        gload16(srcP[c] + kt * 32, dstP[c] + boff);
    }
  };

  auto compute = [&](int kt) {
    const char* L = &Lds[(kt & 1) * BUFB];
    vbf16x8 bf[5];
#pragma unroll
    for (int n = 0; n < 5; ++n)
      bf[n] = *(const vbf16x8*)(L + bRd + n * 1024);
    __builtin_amdgcn_s_setprio(1);
#pragma unroll
    for (int m = 0; m < 4; ++m) {
      vbf16x8 af = *(const vbf16x8*)(L + aRd + m * 1024);
#pragma unroll
      for (int n = 0; n < 5; ++n)
        acc[m][n] = __builtin_amdgcn_mfma_f32_16x16x32_bf16(af, bf[n], acc[m][n], 0, 0, 0);
    }
    __builtin_amdgcn_s_setprio(0);
  };

  // 2-phase: barrier drains tile kt (flew during compute(kt-1)); issue kt+1
  // right after -> flies during compute(kt). FULLY unrolled.
  issue(0);
#pragma unroll
  for (int kt = 0; kt < NKT; ++kt) {
    __syncthreads();
    if (kt < NKT - 1) issue(kt + 1);
    compute(kt);
  }

  // ---- fused epilogue: 5 gates for (row, d) live in acc[m][0..4] ----
  const int dcol = cb * 32 + wc * 16 + lm;
  const float bu  = p.bcx[dcol];
  const float bi  = p.bix[dcol];
  const float bff = p.bfx[dcol];
  const float bo_ = p.box[dcol];
#pragma unroll
  for (int m = 0; m < 4; ++m) {
    const int r0 = rowBase + wr * 64 + m * 16 + lk * 4;
#pragma unroll
    for (int jj = 0; jj < 4; ++jj) {
      const size_t off = (size_t)(r0 + jj) * DDIM + dcol;
      const float pu  = acc[m][0][jj] + bu;
      const float pi  = acc[m][1][jj] + bi;
      const float plf = acc[m][2][jj] + bff;
      const float prf = acc[m][3][jj] + bff;
      const float po  = acc[m][4][jj] + bo_;
      const float u  = tanh_(pu);
      const float ig = sigm(pi);
      const float lf = sigm(plf);
      const float rf = sigm(prf);
      const float og = sigm(po);
      const float c  = ig * u + lf * p.lc[off] + rf * p.rc[off];
      const float hh = og * tanh_(c);
      p.out[off]         = c;
      p.out[NELEM + off] = hh;
    }
  }
}

// ---------------- fallback (R3 kernel, used only if ws too small) ----------------
struct Params {
  const float *x, *lh, *rh, *lc, *rc;
  const float *s0g0, *s0g1, *s0g2, *s0g3, *s0g4;
  const float *s1g0, *s1g1, *s1g2, *s1g3, *s1g4;
  const float *s2g0, *s2g1, *s2g2, *s2g3, *s2g4;
  const float *bcx, *bix, *bfx, *box;
  float *out;
};
__global__ __launch_bounds__(256, 2) void fused_tree_cell_fb(Params p)
{
  const int t   = threadIdx.x;
  const int bid = blockIdx.x;
  const int nbid    = (bid & 7) * 1024 + (bid >> 3);
  const int tileRow = nbid >> 3;
  const int cb      = nbid & 7;
  const int rowBase = tileRow * 128;
  __shared__ short Ash[128 * 64];
  __shared__ short Bsh[160 * 64];
  const int l  = t & 63;
  const int lm = l & 15;
  const int lk = l >> 4;
  const int w  = t >> 6;
  const int wr = w >> 1;
  const int wc = w & 1;
  vf32x4 acc[4][5];
#pragma unroll
  for (int m = 0; m < 4; ++m)
#pragma unroll
    for (int n = 0; n < 5; ++n) acc[m][n] = (vf32x4)(0.f);
  float4 aR[4][2];
  float4 bR[5][2];
  const int tg  = t >> 3;
  const int kc  = (t & 7) * 8;
  const int kcB = kc * 2;
  auto stage_load = [&](int kt) {
    const int seg  = kt >> 2;
    const int ksub = (kt & 3) * 64;
    const float *ap, *g0, *g1, *g2, *g3, *g4;
    if (seg == 0)      { ap = p.x;  g0 = p.s0g0; g1 = p.s0g1; g2 = p.s0g2; g3 = p.s0g3; g4 = p.s0g4; }
    else if (seg == 1) { ap = p.lh; g0 = p.s1g0; g1 = p.s1g1; g2 = p.s1g2; g3 = p.s1g3; g4 = p.s1g4; }
    else               { ap = p.rh; g0 = p.s2g0; g1 = p.s2g1; g2 = p.s2g2; g3 = p.s2g3; g4 = p.s2g4; }
#pragma unroll
    for (int ps = 0; ps < 4; ++ps) {
      const float* s = ap + (size_t)(rowBase + ps * 32 + tg) * DDIM + ksub + kc;
      aR[ps][0] = *(const float4*)s;
      aR[ps][1] = *(const float4*)(s + 4);
    }
#define BLOAD(ps, GA, GB) { \
    const float* bp = (t & 128) ? (GB) : (GA); \
    const int dloc = ((((ps) * 32) + tg) >= 80 ? 16 : 0) + (tg & 15); \
    const float* s = bp + (size_t)(cb * 32 + dloc) * DDIM + ksub + kc; \
    bR[ps][0] = *(const float4*)s; \
    bR[ps][1] = *(const float4*)(s + 4); }
    BLOAD(0, g0, g1) BLOAD(1, g2, g3) BLOAD(2, g4, g0) BLOAD(3, g1, g2) BLOAD(4, g3, g4)
#undef BLOAD
  };
  auto stage_write = [&]() {
    char* Ab = (char*)&Ash[0];
#pragma unroll
    for (int ps = 0; ps < 4; ++ps) {
      const int row  = ps * 32 + tg;
      const int byte = (row * 128 + kcB) ^ ((row & 7) << 4);
      vu32x4 v = { pk2(aR[ps][0].y, aR[ps][0].x), pk2(aR[ps][0].w, aR[ps][0].z),
                   pk2(aR[ps][1].y, aR[ps][1].x), pk2(aR[ps][1].w, aR[ps][1].z) };
      *(vu32x4*)(Ab + byte) = v;
    }
    char* Bb = (char*)&Bsh[0];
#pragma unroll
    for (int ps = 0; ps < 5; ++ps) {
      const int row  = ps * 32 + tg;
      const int byte = (row * 128 + kcB) ^ ((row & 7) << 4);
      vu32x4 v = { pk2(bR[ps][0].y, bR[ps][0].x), pk2(bR[ps][0].w, bR[ps][0].z),
                   pk2(bR[ps][1].y, bR[ps][1].x), pk2(bR[ps][1].w, bR[ps][1].z) };
      *(vu32x4*)(Bb + byte) = v;
    }
  };
  auto compute = [&]() {
    const char* Ab = (const char*)&Ash[0];
    const char* Bb = (const char*)&Bsh[0];
#pragma unroll
    for (int ks = 0; ks < 2; ++ks) {
      vbf16x8 af[4], bf[5];
#pragma unroll
      for (int m = 0; m < 4; ++m) {
        const int row  = wr * 64 + m * 16 + lm;
        const int byte = (row * 128 + ks * 64 + lk * 16) ^ ((row & 7) << 4);
        af[m] = *(const vbf16x8*)(Ab + byte);
      }
#pragma unroll
      for (int n = 0; n < 5; ++n) {
        const int row  = wc * 80 + n * 16 + lm;
        const int byte = (row * 128 + ks * 64 + lk * 16) ^ ((row & 7) << 4);
        bf[n] = *(const vbf16x8*)(Bb + byte);
      }
#pragma unroll
      for (int m = 0; m < 4; ++m)
#pragma unroll
        for (int n = 0; n < 5; ++n)
          acc[m][n] = __builtin_amdgcn_mfma_f32_16x16x32_bf16(af[m], bf[n], acc[m][n], 0, 0, 0);
    }
  };
  stage_load(0);
  stage_write();
  __syncthreads();
  for (int kt = 0; kt < 12; ++kt) {
    if (kt < 11) stage_load(kt + 1);
    compute();
    if (kt < 11) {
      __builtin_amdgcn_sched_barrier(0);
      __builtin_amdgcn_s_barrier();
      stage_write();
      __syncthreads();
    }
  }
  const int dcol = cb * 32 + wc * 16 + lm;
  const float bu  = p.bcx[dcol];
  const float bi  = p.bix[dcol];
  const float bff = p.bfx[dcol];
  const float bo  = p.box[dcol];
#pragma unroll
  for (int m = 0; m < 4; ++m) {
    const int r0 = rowBase + wr * 64 + m * 16 + lk * 4;
#pragma unroll
    for (int jj = 0; jj < 4; ++jj) {
      const size_t off = (size_t)(r0 + jj) * DDIM + dcol;
      const float pu  = acc[m][0][jj] + bu;
      const float pi  = acc[m][1][jj] + bi;
      const float plf = acc[m][2][jj] + bff;
      const float prf = acc[m][3][jj] + bff;
      const float po  = acc[m][4][jj] + bo;
      const float u  = tanh_(pu);
      const float ig = sigm(pi);
      const float lf = sigm(plf);
      const float rf = sigm(prf);
      const float og = sigm(po);
      const float c  = ig * u + lf * p.lc[off] + rf * p.rc[off];
      const float hh = og * tanh_(c);
      p.out[off]         = c;
      p.out[NELEM + off] = hh;
    }
  }
}

extern "C" void kernel_launch(void* const* d_in, const int* in_sizes, int n_in,
                              void* d_out, int out_size, void* d_ws, size_t ws_size,
                              hipStream_t stream)
{
  const float* x  = (const float*)d_in[0];
  const float* lc = (const float*)d_in[1];
  const float* lh = (const float*)d_in[2];
  const float* rc = (const float*)d_in[3];
  const float* rh = (const float*)d_in[4];
  const float* W_cx = (const float*)d_in[5];
  const float* b_cx = (const float*)d_in[6];
  const float* W_ox = (const float*)d_in[7];
  const float* b_ox = (const float*)d_in[8];
  const float* W_fx = (const float*)d_in[9];
  const float* b_fx = (const float*)d_in[10];
  const float* W_ix = (const float*)d_in[11];
  const float* b_ix = (const float*)d_in[12];
  const float* U_ilh  = (const float*)d_in[13];
  const float* U_irh  = (const float*)d_in[14];
  const float* U_lflh = (const float*)d_in[15];
  const float* U_lfrh = (const float*)d_in[16];
  const float* U_rflh = (const float*)d_in[17];
  const float* U_rfrh = (const float*)d_in[18];
  const float* U_ulh  = (const float*)d_in[19];
  const float* U_urh  = (const float*)d_in[20];
  const float* U_olh  = (const float*)d_in[21];
  const float* U_orh  = (const float*)d_in[22];

  if (ws_size >= WS_NEEDED && d_ws != nullptr) {
    unsigned short* A_ws = (unsigned short*)d_ws;
    unsigned short* B_ws = (unsigned short*)((char*)d_ws + WS_B_OFF);
    PPrm q;
    q.w[0] = W_cx;  q.w[1] = W_ix;  q.w[2] = W_fx;   q.w[3] = W_fx;   q.w[4] = W_ox;
    q.w[5] = U_ulh; q.w[6] = U_ilh; q.w[7] = U_lflh; q.w[8] = U_rflh; q.w[9] = U_olh;
    q.w[10] = U_urh; q.w[11] = U_irh; q.w[12] = U_lfrh; q.w[13] = U_rfrh; q.w[14] = U_orh;
    q.x = x; q.lh = lh; q.rh = rh; q.A_ws = A_ws; q.B_ws = B_ws;
    hipLaunchKernelGGL(prep_ab, dim3(NB_A + NB_B), dim3(256), 0, stream, q);
    GPrm g;
    g.A = A_ws; g.B = B_ws; g.lc = lc; g.rc = rc;
    g.bcx = b_cx; g.bix = b_ix; g.bfx = b_fx; g.box = b_ox;
    g.out = (float*)d_out;
    hipLaunchKernelGGL(gemm_fused, dim3(NWG), dim3(256), 0, stream, g);
  } else {
    Params p;
    p.x = x; p.lc = lc; p.lh = lh; p.rc = rc; p.rh = rh;
    p.s0g0 = W_cx;  p.s0g1 = W_ix;  p.s0g2 = W_fx;   p.s0g3 = W_fx;   p.s0g4 = W_ox;
    p.s1g0 = U_ulh; p.s1g1 = U_ilh; p.s1g2 = U_lflh; p.s1g3 = U_rflh; p.s1g4 = U_olh;
    p.s2g0 = U_urh; p.s2g1 = U_irh; p.s2g2 = U_lfrh; p.s2g3 = U_rfrh; p.s2g4 = U_orh;
    p.bcx = b_cx; p.bix = b_ix; p.bfx = b_fx; p.box = b_ox;
    p.out = (float*)d_out;
    hipLaunchKernelGGL(fused_tree_cell_fb, dim3(8192), dim3(256), 0, stream, p);
  }
}

// Round 13
// 512.548 us; speedup vs baseline: 1.1037x; 1.0036x over previous
//
#include <hip/hip_runtime.h>
#include <stdint.h>

#define NROWS   131072
#define DDIM    256
#define KDIM    768                   // 3 segments x 256
#define BM      128
#define BN      160
#define BK      32
#define NKT     (KDIM / BK)           // 24 K-tiles
#define NWG     8192                  // 1024 row tiles x 8 col tiles
#define NELEM   ((size_t)NROWS * DDIM)

#define ABYTES  8192                  // A tile 128x32x2
#define BUFB    18432                 // + B tile 160x32x2 = 10240
#define WS_A_BYTES ((size_t)NROWS * KDIM * 2)          // 201,326,592
#define WS_B_OFF   WS_A_BYTES
#define WS_B_BYTES ((size_t)8 * BN * KDIM * 2)         // 1,966,080
#define WS_NEEDED  (WS_A_BYTES + WS_B_BYTES)

#define NB_B    480                   // prep blocks doing B (122880/256)
#define NB_A    49152                 // prep blocks doing A (131072*96/256)

typedef __attribute__((ext_vector_type(8))) short  vbf16x8;
typedef __attribute__((ext_vector_type(4))) float  vf32x4;
typedef __attribute__((ext_vector_type(4))) unsigned int vu32x4;

__device__ __forceinline__ unsigned pk2(float hi, float lo) {
  return __builtin_amdgcn_perm(__float_as_uint(hi), __float_as_uint(lo), 0x07060302u);
}
__device__ __forceinline__ float sigm(float v)  { return 1.f / (1.f + __expf(-v)); }
__device__ __forceinline__ float tanh_(float v) { return 1.f - 2.f / (1.f + __expf(2.f * v)); }

__device__ __forceinline__ void gload16(const void* g, void* l) {
  __builtin_amdgcn_global_load_lds(
      (const __attribute__((address_space(1))) unsigned int*)g,
      (__attribute__((address_space(3))) unsigned int*)l, 16, 0, 0);
}

// ---- merged prepass (R12-proven): one dispatch. [0,NB_B): B; rest: A ----
struct PPrm {
  const float* w[15];                  // [seg 0..2][gate 0..4]
  const float *x, *lh, *rh;
  unsigned short *A_ws, *B_ws;
};
__global__ __launch_bounds__(256) void prep_ab(PPrm q)
{
  const unsigned bid = blockIdx.x;
  if (bid < NB_B) {
    unsigned gid = bid * 256u + threadIdx.x;        // < 8*160*96
    unsigned cb  = gid / 15360u;
    unsigned rem = gid - cb * 15360u;
    unsigned n   = rem / 96u;
    unsigned gc  = rem - n * 96u;
    unsigned seg  = gc >> 5;
    unsigned gate = (n >= 80u ? n - 80u : n) >> 4;
    unsigned dloc = (n >= 80u ? 16u : 0u) + (n & 15u);
    const float4* s = (const float4*)(q.w[seg * 5 + gate] +
                       (size_t)(cb * 32u + dloc) * 256u + (gc & 31u) * 8u);
    float4 a0 = s[0], a1 = s[1];
    vu32x4 v = { pk2(a0.y, a0.x), pk2(a0.w, a0.z), pk2(a1.y, a1.x), pk2(a1.w, a1.z) };
    *(vu32x4*)(q.B_ws + (size_t)(cb * 160u + n) * 768u + gc * 8u) = v;
  } else {
    unsigned gid = (bid - NB_B) * 256u + threadIdx.x;   // < 131072*96
    unsigned r   = gid / 96u;
    unsigned gc  = gid - r * 96u;                   // 8-elem group 0..95
    const float* src = (gc < 32u) ? q.x : (gc < 64u ? q.lh : q.rh);
    const float4* s = (const float4*)(src + (size_t)r * 256u + (gc & 31u) * 8u);
    float4 a0 = s[0], a1 = s[1];
    vu32x4 v = { pk2(a0.y, a0.x), pk2(a0.w, a0.z), pk2(a1.y, a1.x), pk2(a1.w, a1.z) };
    *(vu32x4*)(q.A_ws + (size_t)r * 768u + gc * 8u) = v;
  }
}

// ---------------- main GEMM + fused epilogue (exact R10 structure) ----------------
struct GPrm {
  const unsigned short *A, *B;
  const float *lc, *rc, *bcx, *bix, *bfx, *box;
  float* out;
};

// Best measured config (R10: GEMM 428 us, occ 45%, VGPR 64):
// 256 thr / 4 waves, wave 64x80, acc[4][5]. BK=32, 2x18KB LDS, rolled K-loop
// (R12 proved unrolling raises VGPR 64->76 and costs occupancy: 443 us).
// 0-conflict XOR swizzle (src-side pre-applied + read-side), XCD A-affinity.
__global__ __launch_bounds__(256, 3) void gemm_fused(GPrm p)
{
  const int t   = threadIdx.x;
  const int bid = blockIdx.x;
  const int j   = bid & 7;             // XCD
  const int g   = bid >> 3;
  const int cb  = g & 7;
  const int rowBase = ((g >> 3) * 8 + j) * BM;

  __shared__ char Lds[2 * BUFB];       // 2 x (A 8KB | B 10KB)

  const int l  = t & 63;
  const int w  = t >> 6;               // 0..3
  const int lm = l & 15;
  const int lk = l >> 4;
  const int wr = w >> 1;               // 0..1: 64 rows each
  const int wc = w & 1;                // 0..1: 80 cols each

  // staging lanes: 1KB/wave-call = 16 rows x 4 x 16B
  const int lr = l >> 2;               // 0..15 row within call
  const int lg = l & 3;                // 0..3  16B group
  const int sw = (lr >> 1) & 3;        // source-side XOR (0-conflict)

  const unsigned short* aSrc = p.A + (size_t)(rowBase + w * 64 + lr) * 768 + (lg ^ sw) * 8;
  const unsigned short* bSrc = p.B + (size_t)(cb * 160 + (w - 2) * 80 + lr) * 768 + (lg ^ sw) * 8;

  // ds_read per-lane base offsets; same XOR on read side (0 conflicts)
  const int xr  = (lk ^ ((lm >> 1) & 3)) << 4;
  const int aRd = (wr * 64 + lm) * 64 + xr;             // + m*1024
  const int bRd = ABYTES + (wc * 80 + lm) * 64 + xr;    // + n*1024

  vf32x4 acc[4][5];
#pragma unroll
  for (int m = 0; m < 4; ++m)
#pragma unroll
    for (int n = 0; n < 5; ++n) acc[m][n] = (vf32x4)(0.f);

  auto issue = [&](int kt, int bo) {
    if (w < 2) {
      const unsigned short* s = aSrc + (size_t)kt * 32;
      char* l0 = &Lds[bo] + w * 4096;
#pragma unroll
      for (int c = 0; c < 4; ++c)
        gload16(s + (size_t)c * 16 * 768, l0 + c * 1024);
    } else {
      const unsigned short* s = bSrc + (size_t)kt * 32;
      char* l0 = &Lds[bo] + ABYTES + (w - 2) * 5120;
#pragma unroll
      for (int c = 0; c < 5; ++c)
        gload16(s + (size_t)c * 16 * 768, l0 + c * 1024);
    }
  };

  auto compute = [&](int bo) {
    const char* L = &Lds[0];
    const int aB = bo + aRd;
    const int bB = bo + bRd;
    vbf16x8 bf[5];
#pragma unroll
    for (int n = 0; n < 5; ++n)
      bf[n] = *(const vbf16x8*)(L + bB + n * 1024);
    __builtin_amdgcn_s_setprio(1);
#pragma unroll
    for (int m = 0; m < 4; ++m) {
      vbf16x8 af = *(const vbf16x8*)(L + aB + m * 1024);
#pragma unroll
      for (int n = 0; n < 5; ++n)
        acc[m][n] = __builtin_amdgcn_mfma_f32_16x16x32_bf16(af, bf[n], acc[m][n], 0, 0, 0);
    }
    __builtin_amdgcn_s_setprio(0);
  };

  issue(0, 0);
#pragma unroll 2
  for (int kt = 0; kt < NKT; ++kt) {
    __syncthreads();
    if (kt < NKT - 1) issue(kt + 1, ((kt + 1) & 1) * BUFB);
    compute((kt & 1) * BUFB);
  }

  // ---- fused epilogue: 5 gates for (row, d) live in acc[m][0..4] ----
  const int dcol = cb * 32 + wc * 16 + lm;
  const float bu  = p.bcx[dcol];
  const float bi  = p.bix[dcol];
  const float bff = p.bfx[dcol];
  const float bo_ = p.box[dcol];
#pragma unroll
  for (int m = 0; m < 4; ++m) {
    const int r0 = rowBase + wr * 64 + m * 16 + lk * 4;
#pragma unroll
    for (int jj = 0; jj < 4; ++jj) {
      const size_t off = (size_t)(r0 + jj) * DDIM + dcol;
      const float pu  = acc[m][0][jj] + bu;
      const float pi  = acc[m][1][jj] + bi;
      const float plf = acc[m][2][jj] + bff;
      const float prf = acc[m][3][jj] + bff;
      const float po  = acc[m][4][jj] + bo_;
      const float u  = tanh_(pu);
      const float ig = sigm(pi);
      const float lf = sigm(plf);
      const float rf = sigm(prf);
      const float og = sigm(po);
      const float c  = ig * u + lf * p.lc[off] + rf * p.rc[off];
      const float hh = og * tanh_(c);
      p.out[off]         = c;
      p.out[NELEM + off] = hh;
    }
  }
}

// ---------------- fallback (R3 kernel, used only if ws too small) ----------------
struct Params {
  const float *x, *lh, *rh, *lc, *rc;
  const float *s0g0, *s0g1, *s0g2, *s0g3, *s0g4;
  const float *s1g0, *s1g1, *s1g2, *s1g3, *s1g4;
  const float *s2g0, *s2g1, *s2g2, *s2g3, *s2g4;
  const float *bcx, *bix, *bfx, *box;
  float *out;
};
__global__ __launch_bounds__(256, 2) void fused_tree_cell_fb(Params p)
{
  const int t   = threadIdx.x;
  const int bid = blockIdx.x;
  const int nbid    = (bid & 7) * 1024 + (bid >> 3);
  const int tileRow = nbid >> 3;
  const int cb      = nbid & 7;
  const int rowBase = tileRow * 128;
  __shared__ short Ash[128 * 64];
  __shared__ short Bsh[160 * 64];
  const int l  = t & 63;
  const int lm = l & 15;
  const int lk = l >> 4;
  const int w  = t >> 6;
  const int wr = w >> 1;
  const int wc = w & 1;
  vf32x4 acc[4][5];
#pragma unroll
  for (int m = 0; m < 4; ++m)
#pragma unroll
    for (int n = 0; n < 5; ++n) acc[m][n] = (vf32x4)(0.f);
  float4 aR[4][2];
  float4 bR[5][2];
  const int tg  = t >> 3;
  const int kc  = (t & 7) * 8;
  const int kcB = kc * 2;
  auto stage_load = [&](int kt) {
    const int seg  = kt >> 2;
    const int ksub = (kt & 3) * 64;
    const float *ap, *g0, *g1, *g2, *g3, *g4;
    if (seg == 0)      { ap = p.x;  g0 = p.s0g0; g1 = p.s0g1; g2 = p.s0g2; g3 = p.s0g3; g4 = p.s0g4; }
    else if (seg == 1) { ap = p.lh; g0 = p.s1g0; g1 = p.s1g1; g2 = p.s1g2; g3 = p.s1g3; g4 = p.s1g4; }
    else               { ap = p.rh; g0 = p.s2g0; g1 = p.s2g1; g2 = p.s2g2; g3 = p.s2g3; g4 = p.s2g4; }
#pragma unroll
    for (int ps = 0; ps < 4; ++ps) {
      const float* s = ap + (size_t)(rowBase + ps * 32 + tg) * DDIM + ksub + kc;
      aR[ps][0] = *(const float4*)s;
      aR[ps][1] = *(const float4*)(s + 4);
    }
#define BLOAD(ps, GA, GB) { \
    const float* bp = (t & 128) ? (GB) : (GA); \
    const int dloc = ((((ps) * 32) + tg) >= 80 ? 16 : 0) + (tg & 15); \
    const float* s = bp + (size_t)(cb * 32 + dloc) * DDIM + ksub + kc; \
    bR[ps][0] = *(const float4*)s; \
    bR[ps][1] = *(const float4*)(s + 4); }
    BLOAD(0, g0, g1) BLOAD(1, g2, g3) BLOAD(2, g4, g0) BLOAD(3, g1, g2) BLOAD(4, g3, g4)
#undef BLOAD
  };
  auto stage_write = [&]() {
    char* Ab = (char*)&Ash[0];
#pragma unroll
    for (int ps = 0; ps < 4; ++ps) {
      const int row  = ps * 32 + tg;
      const int byte = (row * 128 + kcB) ^ ((row & 7) << 4);
      vu32x4 v = { pk2(aR[ps][0].y, aR[ps][0].x), pk2(aR[ps][0].w, aR[ps][0].z),
                   pk2(aR[ps][1].y, aR[ps][1].x), pk2(aR[ps][1].w, aR[ps][1].z) };
      *(vu32x4*)(Ab + byte) = v;
    }
    char* Bb = (char*)&Bsh[0];
#pragma unroll
    for (int ps = 0; ps < 5; ++ps) {
      const int row  = ps * 32 + tg;
      const int byte = (row * 128 + kcB) ^ ((row & 7) << 4);
      vu32x4 v = { pk2(bR[ps][0].y, bR[ps][0].x), pk2(bR[ps][0].w, bR[ps][0].z),
                   pk2(bR[ps][1].y, bR[ps][1].x), pk2(bR[ps][1].w, bR[ps][1].z) };
      *(vu32x4*)(Bb + byte) = v;
    }
  };
  auto compute = [&]() {
    const char* Ab = (const char*)&Ash[0];
    const char* Bb = (const char*)&Bsh[0];
#pragma unroll
    for (int ks = 0; ks < 2; ++ks) {
      vbf16x8 af[4], bf[5];
#pragma unroll
      for (int m = 0; m < 4; ++m) {
        const int row  = wr * 64 + m * 16 + lm;
        const int byte = (row * 128 + ks * 64 + lk * 16) ^ ((row & 7) << 4);
        af[m] = *(const vbf16x8*)(Ab + byte);
      }
#pragma unroll
      for (int n = 0; n < 5; ++n) {
        const int row  = wc * 80 + n * 16 + lm;
        const int byte = (row * 128 + ks * 64 + lk * 16) ^ ((row & 7) << 4);
        bf[n] = *(const vbf16x8*)(Bb + byte);
      }
#pragma unroll
      for (int m = 0; m < 4; ++m)
#pragma unroll
        for (int n = 0; n < 5; ++n)
          acc[m][n] = __builtin_amdgcn_mfma_f32_16x16x32_bf16(af[m], bf[n], acc[m][n], 0, 0, 0);
    }
  };
  stage_load(0);
  stage_write();
  __syncthreads();
  for (int kt = 0; kt < 12; ++kt) {
    if (kt < 11) stage_load(kt + 1);
    compute();
    if (kt < 11) {
      __builtin_amdgcn_sched_barrier(0);
      __builtin_amdgcn_s_barrier();
      stage_write();
      __syncthreads();
    }
  }
  const int dcol = cb * 32 + wc * 16 + lm;
  const float bu  = p.bcx[dcol];
  const float bi  = p.bix[dcol];
  const float bff = p.bfx[dcol];
  const float bo  = p.box[dcol];
#pragma unroll
  for (int m = 0; m < 4; ++m) {
    const int r0 = rowBase + wr * 64 + m * 16 + lk * 4;
#pragma unroll
    for (int jj = 0; jj < 4; ++jj) {
      const size_t off = (size_t)(r0 + jj) * DDIM + dcol;
      const float pu  = acc[m][0][jj] + bu;
      const float pi  = acc[m][1][jj] + bi;
      const float plf = acc[m][2][jj] + bff;
      const float prf = acc[m][3][jj] + bff;
      const float po  = acc[m][4][jj] + bo;
      const float u  = tanh_(pu);
      const float ig = sigm(pi);
      const float lf = sigm(plf);
      const float rf = sigm(prf);
      const float og = sigm(po);
      const float c  = ig * u + lf * p.lc[off] + rf * p.rc[off];
      const float hh = og * tanh_(c);
      p.out[off]         = c;
      p.out[NELEM + off] = hh;
    }
  }
}

extern "C" void kernel_launch(void* const* d_in, const int* in_sizes, int n_in,
                              void* d_out, int out_size, void* d_ws, size_t ws_size,
                              hipStream_t stream)
{
  const float* x  = (const float*)d_in[0];
  const float* lc = (const float*)d_in[1];
  const float* lh = (const float*)d_in[2];
  const float* rc = (const float*)d_in[3];
  const float* rh = (const float*)d_in[4];
  const float* W_cx = (const float*)d_in[5];
  const float* b_cx = (const float*)d_in[6];
  const float* W_ox = (const float*)d_in[7];
  const float* b_ox = (const float*)d_in[8];
  const float* W_fx = (const float*)d_in[9];
  const float* b_fx = (const float*)d_in[10];
  const float* W_ix = (const float*)d_in[11];
  const float* b_ix = (const float*)d_in[12];
  const float* U_ilh  = (const float*)d_in[13];
  const float* U_irh  = (const float*)d_in[14];
  const float* U_lflh = (const float*)d_in[15];
  const float* U_lfrh = (const float*)d_in[16];
  const float* U_rflh = (const float*)d_in[17];
  const float* U_rfrh = (const float*)d_in[18];
  const float* U_ulh  = (const float*)d_in[19];
  const float* U_urh  = (const float*)d_in[20];
  const float* U_olh  = (const float*)d_in[21];
  const float* U_orh  = (const float*)d_in[22];

  if (ws_size >= WS_NEEDED && d_ws != nullptr) {
    unsigned short* A_ws = (unsigned short*)d_ws;
    unsigned short* B_ws = (unsigned short*)((char*)d_ws + WS_B_OFF);
    PPrm q;
    q.w[0] = W_cx;  q.w[1] = W_ix;  q.w[2] = W_fx;   q.w[3] = W_fx;   q.w[4] = W_ox;
    q.w[5] = U_ulh; q.w[6] = U_ilh; q.w[7] = U_lflh; q.w[8] = U_rflh; q.w[9] = U_olh;
    q.w[10] = U_urh; q.w[11] = U_irh; q.w[12] = U_lfrh; q.w[13] = U_rfrh; q.w[14] = U_orh;
    q.x = x; q.lh = lh; q.rh = rh; q.A_ws = A_ws; q.B_ws = B_ws;
    hipLaunchKernelGGL(prep_ab, dim3(NB_A + NB_B), dim3(256), 0, stream, q);
    GPrm g;
    g.A = A_ws; g.B = B_ws; g.lc = lc; g.rc = rc;
    g.bcx = b_cx; g.bix = b_ix; g.bfx = b_fx; g.box = b_ox;
    g.out = (float*)d_out;
    hipLaunchKernelGGL(gemm_fused, dim3(NWG), dim3(256), 0, stream, g);
  } else {
    Params p;
    p.x = x; p.lc = lc; p.lh = lh; p.rc = rc; p.rh = rh;
    p.s0g0 = W_cx;  p.s0g1 = W_ix;  p.s0g2 = W_fx;   p.s0g3 = W_fx;   p.s0g4 = W_ox;
    p.s1g0 = U_ulh; p.s1g1 = U_ilh; p.s1g2 = U_lflh; p.s1g3 = U_rflh; p.s1g4 = U_olh;
    p.s2g0 = U_urh; p.s2g1 = U_irh; p.s2g2 = U_lfrh; p.s2g3 = U_rfrh; p.s2g4 = U_orh;
    p.bcx = b_cx; p.bix = b_ix; p.bfx = b_fx; p.box = b_ox;
    p.out = (float*)d_out;
    hipLaunchKernelGGL(fused_tree_cell_fb, dim3(8192), dim3(256), 0, stream, p);
  }
}